// Round 1
// baseline (761.958 us; speedup 1.0000x reference)
//
#include <hip/hip_runtime.h>
#include <math.h>

// ---------------- graph build ----------------

__global__ void count_kernel(const int* __restrict__ ei, int* __restrict__ cnt, int E) {
  int e = blockIdx.x * 256 + threadIdx.x;
  if (e < E) atomicAdd(&cnt[ei[E + e]], 1);
}

__global__ void scan_block_kernel(const int* __restrict__ cnt, int* __restrict__ part,
                                  int* __restrict__ bsums, float* __restrict__ dis, int n) {
  __shared__ int wsum[4];
  int tid = threadIdx.x;
  int lane = tid & 63, wid = tid >> 6;
  int base = blockIdx.x * 1024 + tid * 4;
  int v0 = 0, v1 = 0, v2 = 0, v3 = 0;
  if (base + 0 < n) { v0 = cnt[base + 0]; dis[base + 0] = 1.f / sqrtf((float)(v0 + 1)); }
  if (base + 1 < n) { v1 = cnt[base + 1]; dis[base + 1] = 1.f / sqrtf((float)(v1 + 1)); }
  if (base + 2 < n) { v2 = cnt[base + 2]; dis[base + 2] = 1.f / sqrtf((float)(v2 + 1)); }
  if (base + 3 < n) { v3 = cnt[base + 3]; dis[base + 3] = 1.f / sqrtf((float)(v3 + 1)); }
  int tot = v0 + v1 + v2 + v3;
  int x = tot;
#pragma unroll
  for (int d = 1; d < 64; d <<= 1) { int y = __shfl_up(x, d, 64); if (lane >= d) x += y; }
  if (lane == 63) wsum[wid] = x;
  __syncthreads();
  int wpre = 0;
#pragma unroll
  for (int w = 0; w < 4; ++w) wpre += (w < wid) ? wsum[w] : 0;
  int ex = wpre + x - tot;
  if (base + 0 < n) part[base + 0] = ex; ex += v0;
  if (base + 1 < n) part[base + 1] = ex; ex += v1;
  if (base + 2 < n) part[base + 2] = ex; ex += v2;
  if (base + 3 < n) part[base + 3] = ex;
  if (tid == 255) bsums[blockIdx.x] = wpre + x;
}

__global__ void scan_tops_kernel(int* __restrict__ bsums, int nb, int* __restrict__ offs, int n) {
  if (threadIdx.x == 0) {
    int run = 0;
    for (int b = 0; b < nb; ++b) { int t = bsums[b]; bsums[b] = run; run += t; }
    offs[n] = run;
  }
}

__global__ void scan_add_kernel(const int* __restrict__ bsums, int* __restrict__ offs,
                                int* __restrict__ cursor, int n) {
  int i = blockIdx.x * 256 + threadIdx.x;
  if (i < n) {
    int o = offs[i] + bsums[i >> 10];
    offs[i] = o;
    cursor[i] = o;
  }
}

__global__ void fill_kernel(const int* __restrict__ ei, int* __restrict__ cursor,
                            int* __restrict__ csr, int E) {
  int e = blockIdx.x * 256 + threadIdx.x;
  if (e < E) {
    int s = ei[e];
    int d = ei[E + e];
    int pos = atomicAdd(&cursor[d], 1);
    csr[pos] = s;
  }
}

// ---------------- fp32 GEMM: C[M,NCOL] = A[M,128] @ W[128,NCOL] (+bias, relu) ----------------

template <int NCOL, bool RELU, bool BIAS>
__global__ __launch_bounds__(512) void gemm_kernel(const float* __restrict__ A,
                                                   const float* __restrict__ W,
                                                   const float* __restrict__ bias,
                                                   float* __restrict__ C, int M) {
  constexpr int TC = NCOL / 16;  // 8 for NCOL=128, 4 for NCOL=64
  __shared__ float As[128][128];
  __shared__ float Ws[128][NCOL];
  int tid = threadIdx.x;
  int row0 = blockIdx.x * 128;
#pragma unroll
  for (int i = 0; i < 8; ++i) {
    int idx = tid + i * 512;          // float4 index over 128x128
    int r = idx >> 5;
    int c = (idx & 31) << 2;
    int gr = row0 + r;
    float4 v = make_float4(0.f, 0.f, 0.f, 0.f);
    if (gr < M) v = *reinterpret_cast<const float4*>(A + (size_t)gr * 128 + c);
    *reinterpret_cast<float4*>(&As[r][c]) = v;
  }
  constexpr int WV = (128 * NCOL / 4) / 512;
#pragma unroll
  for (int i = 0; i < WV; ++i) {
    int idx = tid + i * 512;
    int r = idx / (NCOL / 4);
    int c = (idx % (NCOL / 4)) << 2;
    *reinterpret_cast<float4*>(&Ws[r][c]) = *reinterpret_cast<const float4*>(W + r * NCOL + c);
  }
  __syncthreads();
  int tx = tid & 15, ty4 = (tid >> 4) * 4;
  int cx = tx * TC;
  float acc[4][TC];
#pragma unroll
  for (int r = 0; r < 4; ++r)
#pragma unroll
    for (int c = 0; c < TC; ++c) acc[r][c] = 0.f;
#pragma unroll 8
  for (int k = 0; k < 128; ++k) {
    float a0 = As[ty4 + 0][k], a1 = As[ty4 + 1][k], a2 = As[ty4 + 2][k], a3 = As[ty4 + 3][k];
#pragma unroll
    for (int c = 0; c < TC; ++c) {
      float w = Ws[k][cx + c];
      acc[0][c] = fmaf(a0, w, acc[0][c]);
      acc[1][c] = fmaf(a1, w, acc[1][c]);
      acc[2][c] = fmaf(a2, w, acc[2][c]);
      acc[3][c] = fmaf(a3, w, acc[3][c]);
    }
  }
#pragma unroll
  for (int r = 0; r < 4; ++r) {
    int gr = row0 + ty4 + r;
    if (gr < M) {
#pragma unroll
      for (int c = 0; c < TC; ++c) {
        float v = acc[r][c];
        if (BIAS) v += bias[cx + c];
        if (RELU) v = fmaxf(v, 0.f);
        C[(size_t)gr * NCOL + cx + c] = v;
      }
    }
  }
}

// ---------------- pull-style aggregation ----------------

// z[n,:] = relu( sum_{s in in(n)} h[s,:]*dis[s]*dis[n] + h[n,:]*dis[n]^2 + b )   (128 feats)
__global__ __launch_bounds__(256) void agg1_kernel(const float* __restrict__ h,
                                                   const int* __restrict__ offs,
                                                   const int* __restrict__ csr,
                                                   const float* __restrict__ dis,
                                                   const float* __restrict__ b,
                                                   float* __restrict__ zout, int n) {
  int wid = threadIdx.x >> 6, lane = threadIdx.x & 63;
  int node = blockIdx.x * 4 + wid;
  if (node >= n) return;
  int f = lane * 2;
  float dn = dis[node];
  float2 hv = *reinterpret_cast<const float2*>(h + (size_t)node * 128 + f);
  float sw = dn * dn;
  float ax = hv.x * sw, ay = hv.y * sw;
  int jb = offs[node], je = offs[node + 1];
  for (int bs = jb; bs < je; bs += 64) {
    int idx = bs + lane;
    int sl = 0; float wl = 0.f;
    if (idx < je) { sl = csr[idx]; wl = dis[sl]; }
    int m = je - bs; if (m > 64) m = 64;
    for (int t = 0; t < m; ++t) {
      int s = __shfl(sl, t, 64);
      float w = __shfl(wl, t, 64) * dn;
      float2 v = *reinterpret_cast<const float2*>(h + (size_t)s * 128 + f);
      ax = fmaf(v.x, w, ax);
      ay = fmaf(v.y, w, ay);
    }
  }
  float2 bb = *reinterpret_cast<const float2*>(b + f);
  float2 o;
  o.x = fmaxf(ax + bb.x, 0.f);
  o.y = fmaxf(ay + bb.y, 0.f);
  *reinterpret_cast<float2*>(zout + (size_t)node * 128 + f) = o;
}

// out[n,:] = beta*( agg2 + bg2 ) + (1-beta)*z_mlp[n,:]   (64 feats)
__global__ __launch_bounds__(256) void agg2_kernel(const float* __restrict__ h,
                                                   const int* __restrict__ offs,
                                                   const int* __restrict__ csr,
                                                   const float* __restrict__ dis,
                                                   const float* __restrict__ b,
                                                   const float* __restrict__ zmlp,
                                                   const float* __restrict__ spi,
                                                   const float* __restrict__ logT,
                                                   float* __restrict__ out, int n) {
  int wid = threadIdx.x >> 6, lane = threadIdx.x & 63;
  int node = blockIdx.x * 4 + wid;
  if (node >= n) return;
  float dn = dis[node];
  float acc = h[(size_t)node * 64 + lane] * dn * dn;
  int jb = offs[node], je = offs[node + 1];
  for (int bs = jb; bs < je; bs += 64) {
    int idx = bs + lane;
    int sl = 0; float wl = 0.f;
    if (idx < je) { sl = csr[idx]; wl = dis[sl]; }
    int m = je - bs; if (m > 64) m = 64;
    for (int t = 0; t < m; ++t) {
      int s = __shfl(sl, t, 64);
      float w = __shfl(wl, t, 64) * dn;
      acc = fmaf(h[(size_t)s * 64 + lane], w, acc);
    }
  }
  float beta = 1.f / (1.f + expf(-((spi[0] - 0.67f) / expf(logT[0]))));
  float zg = acc + b[lane];
  out[(size_t)node * 64 + lane] = beta * zg + (1.f - beta) * zmlp[(size_t)node * 64 + lane];
}

// ---------------- launcher ----------------

extern "C" void kernel_launch(void* const* d_in, const int* in_sizes, int n_in,
                              void* d_out, int out_size, void* d_ws, size_t ws_size,
                              hipStream_t stream) {
  const float* x    = (const float*)d_in[0];
  const int*   ei   = (const int*)d_in[1];
  const float* spi  = (const float*)d_in[2];
  const float* Wg1  = (const float*)d_in[3];
  const float* bg1  = (const float*)d_in[4];
  const float* Wg2  = (const float*)d_in[5];
  const float* bg2  = (const float*)d_in[6];
  const float* Wm1  = (const float*)d_in[7];
  const float* bm1  = (const float*)d_in[8];
  const float* Wm2  = (const float*)d_in[9];
  const float* bm2  = (const float*)d_in[10];
  const float* logT = (const float*)d_in[11];
  float* out = (float*)d_out;

  int n = in_sizes[0] / 128;   // 100000
  int E = in_sizes[1] / 2;     // 1600000
  int nb = (n + 1023) / 1024;

  char* p = (char*)d_ws;
  auto alloc = [&](size_t bytes) -> char* {
    char* r = p;
    p += (bytes + 255) & ~(size_t)255;
    return r;
  };
  int*   cnt    = (int*)alloc((size_t)n * 4);
  int*   offs   = (int*)alloc((size_t)(n + 1) * 4);
  int*   cursor = (int*)alloc((size_t)n * 4);
  float* dis    = (float*)alloc((size_t)n * 4);
  int*   bsums  = (int*)alloc((size_t)nb * 4);
  int*   csr    = (int*)alloc((size_t)E * 4);
  float* h1     = (float*)alloc((size_t)n * 128 * 4);  // reused as h2
  float* hm     = (float*)alloc((size_t)n * 128 * 4);
  float* z      = (float*)alloc((size_t)n * 128 * 4);  // reused as z_mlp

  hipMemsetAsync(cnt, 0, (size_t)n * 4, stream);

  int eb = (E + 255) / 256;
  count_kernel<<<eb, 256, 0, stream>>>(ei, cnt, E);
  scan_block_kernel<<<nb, 256, 0, stream>>>(cnt, offs, bsums, dis, n);
  scan_tops_kernel<<<1, 64, 0, stream>>>(bsums, nb, offs, n);
  scan_add_kernel<<<(n + 255) / 256, 256, 0, stream>>>(bsums, offs, cursor, n);
  fill_kernel<<<eb, 256, 0, stream>>>(ei, cursor, csr, E);

  int gb = (n + 127) / 128;
  gemm_kernel<128, false, false><<<gb, 512, 0, stream>>>(x, Wg1, nullptr, h1, n);
  gemm_kernel<128, true,  true ><<<gb, 512, 0, stream>>>(x, Wm1, bm1, hm, n);
  agg1_kernel<<<(n + 3) / 4, 256, 0, stream>>>(h1, offs, csr, dis, bg1, z, n);

  float* h2   = h1;  // h1 dead after agg1
  gemm_kernel<64, false, false><<<gb, 512, 0, stream>>>(z, Wg2, nullptr, h2, n);
  float* zmlp = z;   // z dead after gemm above (stream-ordered)
  gemm_kernel<64, false, true ><<<gb, 512, 0, stream>>>(hm, Wm2, bm2, zmlp, n);

  agg2_kernel<<<(n + 3) / 4, 256, 0, stream>>>(h2, offs, csr, dis, bg2, zmlp, spi, logT, out, n);
}